// Round 1
// baseline (407.314 us; speedup 1.0000x reference)
//
#include <hip/hip_runtime.h>
#include <hip/hip_bf16.h>
#include <cstdint>

#define DIMSZ 1024
#define S_LEN 2048
#define NH 16
#define HD 64

typedef __attribute__((ext_vector_type(4))) float f32x4;
typedef __attribute__((ext_vector_type(8))) __bf16 bf16x8;

#define MFMA_BF16(a,b,c) __builtin_amdgcn_mfma_f32_16x16x32_bf16((a),(b),(c),0,0,0)

__device__ __forceinline__ void gload_lds16(const void* g, void* l) {
  __builtin_amdgcn_global_load_lds(
      (const __attribute__((address_space(1))) unsigned int*)(uintptr_t)g,
      (__attribute__((address_space(3))) unsigned int*)(uintptr_t)l,
      16, 0, 0);
}

// ---------------- cast fp32 -> bf16 ----------------
__global__ __launch_bounds__(256)
void cast_bf16_kernel(const float* __restrict__ in, __hip_bfloat16* __restrict__ out, int n4)
{
  int i = blockIdx.x * 256 + threadIdx.x;
  if (i >= n4) return;
  float4 v = ((const float4*)in)[i];
  __hip_bfloat16* o = out + (size_t)i * 4;
  o[0] = __float2bfloat16(v.x);
  o[1] = __float2bfloat16(v.y);
  o[2] = __float2bfloat16(v.z);
  o[3] = __float2bfloat16(v.w);
}

// ---------------- RMSNorm: fp32 row -> bf16 row ----------------
__global__ __launch_bounds__(256)
void rmsnorm_kernel(const float* __restrict__ x, const float* __restrict__ w,
                    __hip_bfloat16* __restrict__ out)
{
  int row = blockIdx.x;
  int tid = threadIdx.x;
  const float4 v = ((const float4*)(x + (size_t)row * DIMSZ))[tid];
  float ss = v.x*v.x + v.y*v.y + v.z*v.z + v.w*v.w;
  #pragma unroll
  for (int m = 32; m >= 1; m >>= 1) ss += __shfl_xor(ss, m);
  __shared__ float red[4];
  int wave = tid >> 6, lane = tid & 63;
  if (lane == 0) red[wave] = ss;
  __syncthreads();
  float tot = red[0] + red[1] + red[2] + red[3];
  float sc = rsqrtf(tot * (1.0f / DIMSZ) + 1e-6f);
  const float4 wv = ((const float4*)w)[tid];
  __hip_bfloat16* o = out + (size_t)row * DIMSZ + tid * 4;
  o[0] = __float2bfloat16(v.x * sc * wv.x);
  o[1] = __float2bfloat16(v.y * sc * wv.y);
  o[2] = __float2bfloat16(v.z * sc * wv.z);
  o[3] = __float2bfloat16(v.w * sc * wv.w);
}

// ---------------- GEMM: C[M,N] = A[M,K] * B[N,K]^T, bf16 in, fp32 acc ----------------
// EPI 0: store bf16 raw; EPI 1: fp32 store of (resid + acc); EPI 2: bf16 store of silu(acc)
template<int EPI>
__global__ __launch_bounds__(256)
void gemm_bt(const __hip_bfloat16* __restrict__ A,
             const __hip_bfloat16* __restrict__ Bw,
             float* __restrict__ Cf,
             __hip_bfloat16* __restrict__ Cb,
             const float* __restrict__ resid,
             int N, int K)
{
  __shared__ __align__(16) __hip_bfloat16 sA[128 * 32];
  __shared__ __align__(16) __hip_bfloat16 sB[128 * 32];
  const int tid = threadIdx.x;
  const int wave = tid >> 6, lane = tid & 63;
  const int lg = lane >> 4, lr15 = lane & 15;
  const int row0 = blockIdx.y * 128, col0 = blockIdx.x * 128;
  const int wr = wave >> 1, wc = wave & 1;
  f32x4 acc[4][4] = {};

  const int ld_r = tid >> 2;          // 0..63
  const int ld_c = (tid & 3) * 8;
  const __hip_bfloat16* gA = A + (size_t)(row0 + ld_r) * K + ld_c;
  const __hip_bfloat16* gB = Bw + (size_t)(col0 + ld_r) * K + ld_c;

  for (int k0 = 0; k0 < K; k0 += 32) {
    gload_lds16(gA + k0,          &sA[(wave * 64) * 8]);
    gload_lds16(gA + 64 * K + k0, &sA[(256 + wave * 64) * 8]);
    gload_lds16(gB + k0,          &sB[(wave * 64) * 8]);
    gload_lds16(gB + 64 * K + k0, &sB[(256 + wave * 64) * 8]);
    __syncthreads();
    bf16x8 af[4], bfr[4];
    #pragma unroll
    for (int m = 0; m < 4; ++m)
      af[m] = *(const bf16x8*)&sA[(wr * 64 + m * 16 + lr15) * 32 + lg * 8];
    #pragma unroll
    for (int n = 0; n < 4; ++n)
      bfr[n] = *(const bf16x8*)&sB[(wc * 64 + n * 16 + lr15) * 32 + lg * 8];
    #pragma unroll
    for (int m = 0; m < 4; ++m)
      #pragma unroll
      for (int n = 0; n < 4; ++n)
        acc[m][n] = MFMA_BF16(af[m], bfr[n], acc[m][n]);
    __syncthreads();
  }

  #pragma unroll
  for (int m = 0; m < 4; ++m) {
    #pragma unroll
    for (int n = 0; n < 4; ++n) {
      #pragma unroll
      for (int r = 0; r < 4; ++r) {
        const int grow = row0 + wr * 64 + m * 16 + lg * 4 + r;
        const int gcol = col0 + wc * 64 + n * 16 + lr15;
        const size_t idx = (size_t)grow * N + gcol;
        const float v = acc[m][n][r];
        if (EPI == 0) {
          Cb[idx] = __float2bfloat16(v);
        } else if (EPI == 1) {
          Cf[idx] = resid[idx] + v;
        } else {
          Cb[idx] = __float2bfloat16(v / (1.0f + __expf(-v)));
        }
      }
    }
  }
}

// ---------------- RoPE on q,k: qkv[B,S,3*1024] bf16 -> Q,K [B,H,S,64] bf16 ----------------
__global__ __launch_bounds__(256)
void rope_qk(const __hip_bfloat16* __restrict__ qkv,
             __hip_bfloat16* __restrict__ Q, __hip_bfloat16* __restrict__ Kx)
{
  int idx = blockIdx.x * 256 + threadIdx.x;   // bits: i:5, h:4, s:11, b:1
  int i = idx & 31;
  int h = (idx >> 5) & 15;
  int s = (idx >> 9) & (S_LEN - 1);
  int b = idx >> 20;
  const size_t base = ((size_t)b * S_LEN + s) * 3072 + h * 64 + 2 * i;
  float qe = __bfloat162float(qkv[base]);
  float qo = __bfloat162float(qkv[base + 1]);
  float ke = __bfloat162float(qkv[base + 1024]);
  float ko = __bfloat162float(qkv[base + 1025]);
  // inv_freq = 10000^(-2i/64) = exp(-(2i/64)*ln(10000))
  float inv = __expf(-(2.0f * i) * (9.210340371976184f / 64.0f));
  float ang = (float)s * inv;
  float sn, cs;
  __sincosf(ang, &sn, &cs);
  const float sc = 0.125f;   // 1/sqrt(HD) folded into Q
  size_t qb = (((size_t)b * NH + h) * S_LEN + s) * HD + 2 * i;
  Q[qb]     = __float2bfloat16((qe * cs - qo * sn) * sc);
  Q[qb + 1] = __float2bfloat16((qo * cs + qe * sn) * sc);
  Kx[qb]     = __float2bfloat16(ke * cs - ko * sn);
  Kx[qb + 1] = __float2bfloat16(ko * cs + ke * sn);
}

// ---------------- V transpose: qkv v-part -> Vt [B,H,64,S] ----------------
__global__ __launch_bounds__(256)
void v_transpose(const __hip_bfloat16* __restrict__ qkv, __hip_bfloat16* __restrict__ Vt)
{
  __shared__ __hip_bfloat16 t[64][72];
  const int s0 = blockIdx.x * 64;
  const int bh = blockIdx.y;
  const int b = bh >> 4, h = bh & 15;
  const int tid = threadIdx.x;
  const int c = tid & 63;
  #pragma unroll
  for (int r = 0; r < 16; ++r) {
    int srow = r * 4 + (tid >> 6);
    t[srow][c] = qkv[((size_t)b * S_LEN + s0 + srow) * 3072 + 2048 + h * 64 + c];
  }
  __syncthreads();
  #pragma unroll
  for (int r = 0; r < 16; ++r) {
    int drow = r * 4 + (tid >> 6);
    Vt[(((size_t)b * NH + h) * HD + drow) * S_LEN + s0 + c] = t[c][drow];
  }
}

// ---------------- flash attention: 1 wave per 16 q-rows, causal ----------------
__global__ __launch_bounds__(64)
void flash_attn(const __hip_bfloat16* __restrict__ Q,
                const __hip_bfloat16* __restrict__ Kx,
                const __hip_bfloat16* __restrict__ Vt,
                __hip_bfloat16* __restrict__ attn)
{
  __shared__ __align__(16) __hip_bfloat16 sP[16 * 32];
  const int lane = threadIdx.x;
  const int lg = lane >> 4, lr = lane & 15;
  const int tile = blockIdx.x;
  const int qt = tile & 127;
  const int h = (tile >> 7) & 15;
  const int b = tile >> 11;
  const int q0 = qt * 16;
  const __hip_bfloat16* Qp = Q + ((size_t)b * NH + h) * S_LEN * HD;
  const __hip_bfloat16* Kp = Kx + ((size_t)b * NH + h) * S_LEN * HD;
  const __hip_bfloat16* Vp = Vt + ((size_t)b * NH + h) * HD * S_LEN;
  const bf16x8 qf0 = *(const bf16x8*)&Qp[(q0 + lr) * HD + lg * 8];
  const bf16x8 qf1 = *(const bf16x8*)&Qp[(q0 + lr) * HD + 32 + lg * 8];
  f32x4 acc[4] = {};
  float mrow[4] = {-1e30f, -1e30f, -1e30f, -1e30f};
  float lrow[4] = {0.f, 0.f, 0.f, 0.f};
  const int kmax = q0 + 16;
  for (int k0 = 0; k0 < kmax; k0 += 32) {
    f32x4 sv[2];
    #pragma unroll
    for (int half = 0; half < 2; ++half) {
      const int kc = k0 + half * 16;
      bf16x8 kf0 = *(const bf16x8*)&Kp[(kc + lr) * HD + lg * 8];
      bf16x8 kf1 = *(const bf16x8*)&Kp[(kc + lr) * HD + 32 + lg * 8];
      f32x4 z = {};
      z = MFMA_BF16(qf0, kf0, z);
      z = MFMA_BF16(qf1, kf1, z);
      sv[half] = z;
    }
    #pragma unroll
    for (int r = 0; r < 4; ++r) {
      const int qpos = q0 + lg * 4 + r;
      float s0 = (k0 + lr      <= qpos) ? sv[0][r] : -1e30f;
      float s1 = (k0 + 16 + lr <= qpos) ? sv[1][r] : -1e30f;
      float mx = fmaxf(s0, s1);
      #pragma unroll
      for (int mm = 1; mm < 16; mm <<= 1) mx = fmaxf(mx, __shfl_xor(mx, mm));
      const float mnew = fmaxf(mrow[r], mx);
      const float corr = __expf(mrow[r] - mnew);
      const float p0 = __expf(s0 - mnew);
      const float p1 = __expf(s1 - mnew);
      float ps = p0 + p1;
      #pragma unroll
      for (int mm = 1; mm < 16; mm <<= 1) ps += __shfl_xor(ps, mm);
      lrow[r] = lrow[r] * corr + ps;
      mrow[r] = mnew;
      #pragma unroll
      for (int dt = 0; dt < 4; ++dt) acc[dt][r] *= corr;
      sP[(lg * 4 + r) * 32 + lr]      = __float2bfloat16(p0);
      sP[(lg * 4 + r) * 32 + 16 + lr] = __float2bfloat16(p1);
    }
    __syncthreads();
    const bf16x8 pa = *(const bf16x8*)&sP[lr * 32 + lg * 8];
    #pragma unroll
    for (int dt = 0; dt < 4; ++dt) {
      bf16x8 vf = *(const bf16x8*)&Vp[(size_t)(dt * 16 + lr) * S_LEN + k0 + lg * 8];
      acc[dt] = MFMA_BF16(pa, vf, acc[dt]);
    }
    __syncthreads();
  }
  #pragma unroll
  for (int r = 0; r < 4; ++r) {
    const float inv_l = 1.0f / lrow[r];
    const size_t rowb = ((size_t)b * S_LEN + q0 + lg * 4 + r) * DIMSZ + h * HD;
    #pragma unroll
    for (int dt = 0; dt < 4; ++dt)
      attn[rowb + dt * 16 + lr] = __float2bfloat16(acc[dt][r] * inv_l);
  }
}

extern "C" void kernel_launch(void* const* d_in, const int* in_sizes, int n_in,
                              void* d_out, int out_size, void* d_ws, size_t ws_size,
                              hipStream_t stream)
{
  const float* x      = (const float*)d_in[0];
  const float* w_in   = (const float*)d_in[1];
  const float* w_ff   = (const float*)d_in[2];
  const float* w_qkv  = (const float*)d_in[3];
  const float* w_out  = (const float*)d_in[4];
  const float* w_fc   = (const float*)d_in[5];
  const float* w_proj = (const float*)d_in[6];
  float* out = (float*)d_out;
  char* ws = (char*)d_ws;

  // workspace layout (bytes); total use = 75,497,472
  __hip_bfloat16* wq_b   = (__hip_bfloat16*)(ws);               // 6,291,456
  __hip_bfloat16* wo_b   = (__hip_bfloat16*)(ws + 6291456);     // 2,097,152
  __hip_bfloat16* wfc_b  = (__hip_bfloat16*)(ws + 8388608);     // 4,194,304
  __hip_bfloat16* wpr_b  = (__hip_bfloat16*)(ws + 12582912);    // 4,194,304
  __hip_bfloat16* h_b    = (__hip_bfloat16*)(ws + 16777216);    // 8,388,608  (reused as h2)
  __hip_bfloat16* qkv_b  = (__hip_bfloat16*)(ws + 25165824);    // 25,165,824
  __hip_bfloat16* attn_b = (__hip_bfloat16*)(ws + 25165824);    // reuse qkv[0:8M]
  __hip_bfloat16* hid_b  = (__hip_bfloat16*)(ws + 33554432);    // reuse qkv[8M:24M]
  __hip_bfloat16* Q_b    = (__hip_bfloat16*)(ws + 50331648);    // 8,388,608
  __hip_bfloat16* K_b    = (__hip_bfloat16*)(ws + 58720256);    // 8,388,608
  __hip_bfloat16* Vt_b   = (__hip_bfloat16*)(ws + 67108864);    // 8,388,608
  float*          x1     = (float*)(ws + 50331648);             // reuse Q+K region after flash

  // 1. weight casts
  cast_bf16_kernel<<<(3072 * 1024 / 4 + 255) / 256, 256, 0, stream>>>(w_qkv, wq_b, 3072 * 1024 / 4);
  cast_bf16_kernel<<<(1024 * 1024 / 4 + 255) / 256, 256, 0, stream>>>(w_out, wo_b, 1024 * 1024 / 4);
  cast_bf16_kernel<<<(2048 * 1024 / 4 + 255) / 256, 256, 0, stream>>>(w_fc, wfc_b, 2048 * 1024 / 4);
  cast_bf16_kernel<<<(1024 * 2048 / 4 + 255) / 256, 256, 0, stream>>>(w_proj, wpr_b, 1024 * 2048 / 4);
  // 2. pre-attn RMSNorm
  rmsnorm_kernel<<<4096, 256, 0, stream>>>(x, w_in, h_b);
  // 3. QKV GEMM -> bf16 qkv
  gemm_bt<0><<<dim3(3072 / 128, 4096 / 128), 256, 0, stream>>>(h_b, wq_b, nullptr, qkv_b, nullptr, 3072, 1024);
  // 4. RoPE q,k + V transpose
  rope_qk<<<2097152 / 256, 256, 0, stream>>>(qkv_b, Q_b, K_b);
  v_transpose<<<dim3(32, 32), 256, 0, stream>>>(qkv_b, Vt_b);
  // 5. flash attention
  flash_attn<<<4096, 64, 0, stream>>>(Q_b, K_b, Vt_b, attn_b);
  // 6. out-proj + residual -> x1 (fp32)
  gemm_bt<1><<<dim3(1024 / 128, 4096 / 128), 256, 0, stream>>>(attn_b, wo_b, x1, nullptr, x, 1024, 1024);
  // 7. pre-FF RMSNorm
  rmsnorm_kernel<<<4096, 256, 0, stream>>>(x1, w_ff, h_b);
  // 8. FC GEMM + SiLU -> bf16 hid
  gemm_bt<2><<<dim3(2048 / 128, 4096 / 128), 256, 0, stream>>>(h_b, wfc_b, nullptr, hid_b, nullptr, 2048, 1024);
  // 9. proj GEMM + residual -> out (fp32)
  gemm_bt<1><<<dim3(1024 / 128, 4096 / 128), 256, 0, stream>>>(hid_b, wpr_b, out, nullptr, x1, 1024, 2048);
}

// Round 2
// 403.169 us; speedup vs baseline: 1.0103x; 1.0103x over previous
//
#include <hip/hip_runtime.h>
#include <hip/hip_bf16.h>
#include <cstdint>

#define DIMSZ 1024
#define S_LEN 2048
#define NH 16
#define HD 64

typedef __attribute__((ext_vector_type(4))) float f32x4;
typedef __attribute__((ext_vector_type(8))) __bf16 bf16x8;

#define MFMA_BF16(a,b,c) __builtin_amdgcn_mfma_f32_16x16x32_bf16((a),(b),(c),0,0,0)

__device__ __forceinline__ void gload_lds16(const void* g, void* l) {
  __builtin_amdgcn_global_load_lds(
      (const __attribute__((address_space(1))) unsigned int*)(uintptr_t)g,
      (__attribute__((address_space(3))) unsigned int*)(uintptr_t)l,
      16, 0, 0);
}

// ---------------- cast fp32 -> bf16 ----------------
__global__ __launch_bounds__(256)
void cast_bf16_kernel(const float* __restrict__ in, __hip_bfloat16* __restrict__ out, int n4)
{
  int i = blockIdx.x * 256 + threadIdx.x;
  if (i >= n4) return;
  float4 v = ((const float4*)in)[i];
  __hip_bfloat16* o = out + (size_t)i * 4;
  o[0] = __float2bfloat16(v.x);
  o[1] = __float2bfloat16(v.y);
  o[2] = __float2bfloat16(v.z);
  o[3] = __float2bfloat16(v.w);
}

// ---------------- RMSNorm: fp32 row -> bf16 row ----------------
__global__ __launch_bounds__(256)
void rmsnorm_kernel(const float* __restrict__ x, const float* __restrict__ w,
                    __hip_bfloat16* __restrict__ out)
{
  int row = blockIdx.x;
  int tid = threadIdx.x;
  const float4 v = ((const float4*)(x + (size_t)row * DIMSZ))[tid];
  float ss = v.x*v.x + v.y*v.y + v.z*v.z + v.w*v.w;
  #pragma unroll
  for (int m = 32; m >= 1; m >>= 1) ss += __shfl_xor(ss, m);
  __shared__ float red[4];
  int wave = tid >> 6, lane = tid & 63;
  if (lane == 0) red[wave] = ss;
  __syncthreads();
  float tot = red[0] + red[1] + red[2] + red[3];
  float sc = rsqrtf(tot * (1.0f / DIMSZ) + 1e-6f);
  const float4 wv = ((const float4*)w)[tid];
  __hip_bfloat16* o = out + (size_t)row * DIMSZ + tid * 4;
  o[0] = __float2bfloat16(v.x * sc * wv.x);
  o[1] = __float2bfloat16(v.y * sc * wv.y);
  o[2] = __float2bfloat16(v.z * sc * wv.z);
  o[3] = __float2bfloat16(v.w * sc * wv.w);
}

// ---------------- GEMM: C[M,N] = A[M,K] * B[N,K]^T, bf16 in, fp32 acc ----------------
template<int EPI>
__global__ __launch_bounds__(256)
void gemm_bt(const __hip_bfloat16* __restrict__ A,
             const __hip_bfloat16* __restrict__ Bw,
             float* __restrict__ Cf,
             __hip_bfloat16* __restrict__ Cb,
             const float* __restrict__ resid,
             int N, int K)
{
  __shared__ __align__(16) __hip_bfloat16 sA[128 * 32];
  __shared__ __align__(16) __hip_bfloat16 sB[128 * 32];
  const int tid = threadIdx.x;
  const int wave = tid >> 6, lane = tid & 63;
  const int lg = lane >> 4, lr15 = lane & 15;
  const int row0 = blockIdx.y * 128, col0 = blockIdx.x * 128;
  const int wr = wave >> 1, wc = wave & 1;
  f32x4 acc[4][4] = {};

  const int ld_r = tid >> 2;          // 0..63
  const int ld_c = (tid & 3) * 8;
  const __hip_bfloat16* gA = A + (size_t)(row0 + ld_r) * K + ld_c;
  const __hip_bfloat16* gB = Bw + (size_t)(col0 + ld_r) * K + ld_c;

  for (int k0 = 0; k0 < K; k0 += 32) {
    gload_lds16(gA + k0,          &sA[(wave * 64) * 8]);
    gload_lds16(gA + 64 * K + k0, &sA[(256 + wave * 64) * 8]);
    gload_lds16(gB + k0,          &sB[(wave * 64) * 8]);
    gload_lds16(gB + 64 * K + k0, &sB[(256 + wave * 64) * 8]);
    __syncthreads();
    bf16x8 af[4], bfr[4];
    #pragma unroll
    for (int m = 0; m < 4; ++m)
      af[m] = *(const bf16x8*)&sA[(wr * 64 + m * 16 + lr15) * 32 + lg * 8];
    #pragma unroll
    for (int n = 0; n < 4; ++n)
      bfr[n] = *(const bf16x8*)&sB[(wc * 64 + n * 16 + lr15) * 32 + lg * 8];
    #pragma unroll
    for (int m = 0; m < 4; ++m)
      #pragma unroll
      for (int n = 0; n < 4; ++n)
        acc[m][n] = MFMA_BF16(af[m], bfr[n], acc[m][n]);
    __syncthreads();
  }

  #pragma unroll
  for (int m = 0; m < 4; ++m) {
    #pragma unroll
    for (int n = 0; n < 4; ++n) {
      #pragma unroll
      for (int r = 0; r < 4; ++r) {
        const int grow = row0 + wr * 64 + m * 16 + lg * 4 + r;
        const int gcol = col0 + wc * 64 + n * 16 + lr15;
        const size_t idx = (size_t)grow * N + gcol;
        const float v = acc[m][n][r];
        if (EPI == 0) {
          Cb[idx] = __float2bfloat16(v);
        } else if (EPI == 1) {
          Cf[idx] = resid[idx] + v;
        } else {
          Cb[idx] = __float2bfloat16(v / (1.0f + __expf(-v)));
        }
      }
    }
  }
}

// ---------------- RoPE on q,k ----------------
__global__ __launch_bounds__(256)
void rope_qk(const __hip_bfloat16* __restrict__ qkv,
             __hip_bfloat16* __restrict__ Q, __hip_bfloat16* __restrict__ Kx)
{
  int idx = blockIdx.x * 256 + threadIdx.x;   // bits: i:5, h:4, s:11, b:1
  int i = idx & 31;
  int h = (idx >> 5) & 15;
  int s = (idx >> 9) & (S_LEN - 1);
  int b = idx >> 20;
  const size_t base = ((size_t)b * S_LEN + s) * 3072 + h * 64 + 2 * i;
  float qe = __bfloat162float(qkv[base]);
  float qo = __bfloat162float(qkv[base + 1]);
  float ke = __bfloat162float(qkv[base + 1024]);
  float ko = __bfloat162float(qkv[base + 1025]);
  float inv = __expf(-(2.0f * i) * (9.210340371976184f / 64.0f));
  float ang = (float)s * inv;
  float sn, cs;
  __sincosf(ang, &sn, &cs);
  const float sc = 0.125f;   // 1/sqrt(HD) folded into Q
  size_t qb = (((size_t)b * NH + h) * S_LEN + s) * HD + 2 * i;
  Q[qb]     = __float2bfloat16((qe * cs - qo * sn) * sc);
  Q[qb + 1] = __float2bfloat16((qo * cs + qe * sn) * sc);
  Kx[qb]     = __float2bfloat16(ke * cs - ko * sn);
  Kx[qb + 1] = __float2bfloat16(ko * cs + ke * sn);
}

// ---------------- V transpose ----------------
__global__ __launch_bounds__(256)
void v_transpose(const __hip_bfloat16* __restrict__ qkv, __hip_bfloat16* __restrict__ Vt)
{
  __shared__ __hip_bfloat16 t[64][72];
  const int s0 = blockIdx.x * 64;
  const int bh = blockIdx.y;
  const int b = bh >> 4, h = bh & 15;
  const int tid = threadIdx.x;
  const int c = tid & 63;
  #pragma unroll
  for (int r = 0; r < 16; ++r) {
    int srow = r * 4 + (tid >> 6);
    t[srow][c] = qkv[((size_t)b * S_LEN + s0 + srow) * 3072 + 2048 + h * 64 + c];
  }
  __syncthreads();
  #pragma unroll
  for (int r = 0; r < 16; ++r) {
    int drow = r * 4 + (tid >> 6);
    Vt[(((size_t)b * NH + h) * HD + drow) * S_LEN + s0 + c] = t[c][drow];
  }
}

// ---------------- flash attention v2: swapped QK^T, no online max ----------------
// 1 wave per 16 q-rows. KVBLK=64. Lane (lg,lr): after QK, holds
// S[k = k0+16t+lg*4+r][q = q0+lr]. Denominator accumulates in-lane (q=lr),
// reduced across lane-groups once at the end. P goes through a 2KB
// XOR-swizzled LDS buffer to become the PV A-fragment.
__device__ __forceinline__ unsigned bf16pack2(float a, float b) {
  __hip_bfloat16 ha = __float2bfloat16(a), hb = __float2bfloat16(b);
  unsigned ua = *reinterpret_cast<unsigned short*>(&ha);
  unsigned ub = *reinterpret_cast<unsigned short*>(&hb);
  return ua | (ub << 16);
}

__global__ __launch_bounds__(64)
void flash_attn2(const __hip_bfloat16* __restrict__ Q,
                 const __hip_bfloat16* __restrict__ Kx,
                 const __hip_bfloat16* __restrict__ Vt,
                 __hip_bfloat16* __restrict__ attn)
{
  __shared__ __align__(16) char sP[2048];   // 16 q-rows x 64 k (bf16), swizzled
  const int lane = threadIdx.x;
  const int lg = lane >> 4, lr = lane & 15;
  const int bid = blockIdx.x;
  const int qt = 127 - (bid & 127);          // heavy causal tiles dispatch first
  const int bh = bid >> 7;                   // 0..31
  const int b = bh >> 4, h = bh & 15;
  const int q0 = qt * 16;
  const __hip_bfloat16* Qp = Q + (size_t)bh * S_LEN * HD;
  const __hip_bfloat16* Kp = Kx + (size_t)bh * S_LEN * HD;
  const __hip_bfloat16* Vp = Vt + (size_t)bh * HD * S_LEN;

  const bf16x8 qf0 = *(const bf16x8*)&Qp[(q0 + lr) * HD + lg * 8];
  const bf16x8 qf1 = *(const bf16x8*)&Qp[(q0 + lr) * HD + 32 + lg * 8];
  f32x4 acc[4] = {};       // acc[dt]: attn[q=lg*4+r][d=dt*16+lr]
  float lsum = 0.f;        // partial denominator for q = lr
  const int kmax = q0 + 16;
  const int nsteps = (kmax + 63) >> 6;
  const int swz = (lr & 7) << 4;

  for (int st = 0; st < nsteps; ++st) {
    const int k0 = st << 6;
    const bool last = (st == nsteps - 1);
    // --- QK^T (swapped): 4 k-tiles of 16 ---
    f32x4 sv[4];
    #pragma unroll
    for (int t = 0; t < 4; ++t) {
      const int krow = k0 + t * 16 + lr;     // always < S_LEN (nsteps*64 <= 2048)
      const bf16x8 kf0 = *(const bf16x8*)&Kp[krow * HD + lg * 8];
      const bf16x8 kf1 = *(const bf16x8*)&Kp[krow * HD + 32 + lg * 8];
      f32x4 z = {};
      z = MFMA_BF16(kf0, qf0, z);
      z = MFMA_BF16(kf1, qf1, z);
      sv[t] = z;
    }
    // --- P = exp(S), unnormalized; in-lane denominator; write to LDS ---
    #pragma unroll
    for (int t = 0; t < 4; ++t) {
      float p[4];
      #pragma unroll
      for (int r = 0; r < 4; ++r) {
        float e = __expf(fminf(sv[t][r], 30.f));
        if (last) {
          const int kg = k0 + t * 16 + lg * 4 + r;
          e = (kg <= q0 + lr) ? e : 0.f;     // causal mask (q = lr)
        }
        lsum += e;
        p[r] = e;
      }
      uint2 w;
      w.x = bf16pack2(p[0], p[1]);
      w.y = bf16pack2(p[2], p[3]);
      *(uint2*)(sP + lr * 128 + ((t * 32 + lg * 8) ^ swz)) = w;
    }
    __syncthreads();   // 1-wave block: just drains LDS writes
    // --- PV: A-fragments from LDS, V from global ---
    const bf16x8 pa0 = *(const bf16x8*)(sP + lr * 128 + ((lg * 16) ^ swz));
    const bf16x8 pa1 = *(const bf16x8*)(sP + lr * 128 + ((64 + lg * 16) ^ swz));
    #pragma unroll
    for (int dt = 0; dt < 4; ++dt) {
      const bf16x8 vf0 = *(const bf16x8*)&Vp[(size_t)(dt * 16 + lr) * S_LEN + k0 + lg * 8];
      const bf16x8 vf1 = *(const bf16x8*)&Vp[(size_t)(dt * 16 + lr) * S_LEN + k0 + 32 + lg * 8];
      acc[dt] = MFMA_BF16(pa0, vf0, acc[dt]);
      acc[dt] = MFMA_BF16(pa1, vf1, acc[dt]);
    }
    __syncthreads();   // reads done before next-step overwrite
  }

  // reduce denominator across the 4 lane-groups (q = lr)
  lsum += __shfl_xor(lsum, 16);
  lsum += __shfl_xor(lsum, 32);
  #pragma unroll
  for (int r = 0; r < 4; ++r) {
    const float li = __shfl(lsum, lg * 4 + r);   // denominator for q = lg*4+r
    const float rli = 1.0f / li;
    const size_t rowb = ((size_t)b * S_LEN + q0 + lg * 4 + r) * DIMSZ + h * HD;
    #pragma unroll
    for (int dt = 0; dt < 4; ++dt)
      attn[rowb + dt * 16 + lr] = __float2bfloat16(acc[dt][r] * rli);
  }
}

extern "C" void kernel_launch(void* const* d_in, const int* in_sizes, int n_in,
                              void* d_out, int out_size, void* d_ws, size_t ws_size,
                              hipStream_t stream)
{
  const float* x      = (const float*)d_in[0];
  const float* w_in   = (const float*)d_in[1];
  const float* w_ff   = (const float*)d_in[2];
  const float* w_qkv  = (const float*)d_in[3];
  const float* w_out  = (const float*)d_in[4];
  const float* w_fc   = (const float*)d_in[5];
  const float* w_proj = (const float*)d_in[6];
  float* out = (float*)d_out;
  char* ws = (char*)d_ws;

  __hip_bfloat16* wq_b   = (__hip_bfloat16*)(ws);               // 6,291,456
  __hip_bfloat16* wo_b   = (__hip_bfloat16*)(ws + 6291456);     // 2,097,152
  __hip_bfloat16* wfc_b  = (__hip_bfloat16*)(ws + 8388608);     // 4,194,304
  __hip_bfloat16* wpr_b  = (__hip_bfloat16*)(ws + 12582912);    // 4,194,304
  __hip_bfloat16* h_b    = (__hip_bfloat16*)(ws + 16777216);    // 8,388,608
  __hip_bfloat16* qkv_b  = (__hip_bfloat16*)(ws + 25165824);    // 25,165,824
  __hip_bfloat16* attn_b = (__hip_bfloat16*)(ws + 25165824);    // reuse qkv[0:8M]
  __hip_bfloat16* hid_b  = (__hip_bfloat16*)(ws + 33554432);    // reuse qkv[8M:24M]
  __hip_bfloat16* Q_b    = (__hip_bfloat16*)(ws + 50331648);    // 8,388,608
  __hip_bfloat16* K_b    = (__hip_bfloat16*)(ws + 58720256);    // 8,388,608
  __hip_bfloat16* Vt_b   = (__hip_bfloat16*)(ws + 67108864);    // 8,388,608
  float*          x1     = (float*)(ws + 50331648);             // reuse Q+K after flash

  cast_bf16_kernel<<<(3072 * 1024 / 4 + 255) / 256, 256, 0, stream>>>(w_qkv, wq_b, 3072 * 1024 / 4);
  cast_bf16_kernel<<<(1024 * 1024 / 4 + 255) / 256, 256, 0, stream>>>(w_out, wo_b, 1024 * 1024 / 4);
  cast_bf16_kernel<<<(2048 * 1024 / 4 + 255) / 256, 256, 0, stream>>>(w_fc, wfc_b, 2048 * 1024 / 4);
  cast_bf16_kernel<<<(1024 * 2048 / 4 + 255) / 256, 256, 0, stream>>>(w_proj, wpr_b, 1024 * 2048 / 4);
  rmsnorm_kernel<<<4096, 256, 0, stream>>>(x, w_in, h_b);
  gemm_bt<0><<<dim3(3072 / 128, 4096 / 128), 256, 0, stream>>>(h_b, wq_b, nullptr, qkv_b, nullptr, 3072, 1024);
  rope_qk<<<2097152 / 256, 256, 0, stream>>>(qkv_b, Q_b, K_b);
  v_transpose<<<dim3(32, 32), 256, 0, stream>>>(qkv_b, Vt_b);
  flash_attn2<<<4096, 64, 0, stream>>>(Q_b, K_b, Vt_b, attn_b);
  gemm_bt<1><<<dim3(1024 / 128, 4096 / 128), 256, 0, stream>>>(attn_b, wo_b, x1, nullptr, x, 1024, 1024);
  rmsnorm_kernel<<<4096, 256, 0, stream>>>(x1, w_ff, h_b);
  gemm_bt<2><<<dim3(2048 / 128, 4096 / 128), 256, 0, stream>>>(h_b, wfc_b, nullptr, hid_b, nullptr, 2048, 1024);
  gemm_bt<1><<<dim3(1024 / 128, 4096 / 128), 256, 0, stream>>>(hid_b, wpr_b, out, nullptr, x1, 1024, 2048);
}

// Round 3
// 218.574 us; speedup vs baseline: 1.8635x; 1.8445x over previous
//
#include <hip/hip_runtime.h>
#include <hip/hip_bf16.h>
#include <cstdint>

#define DIMSZ 1024
#define S_LEN 2048
#define NH 16
#define HD 64

typedef __attribute__((ext_vector_type(4))) float f32x4;
typedef __attribute__((ext_vector_type(8))) __bf16 bf16x8;

#define MFMA_BF16(a,b,c) __builtin_amdgcn_mfma_f32_16x16x32_bf16((a),(b),(c),0,0,0)

__device__ __forceinline__ void gload_lds16(const void* g, void* l) {
  __builtin_amdgcn_global_load_lds(
      (const __attribute__((address_space(1))) unsigned int*)(uintptr_t)g,
      (__attribute__((address_space(3))) unsigned int*)(uintptr_t)l,
      16, 0, 0);
}

// ---------------- cast fp32 -> bf16 ----------------
__global__ __launch_bounds__(256)
void cast_bf16_kernel(const float* __restrict__ in, __hip_bfloat16* __restrict__ out, int n4)
{
  int i = blockIdx.x * 256 + threadIdx.x;
  if (i >= n4) return;
  float4 v = ((const float4*)in)[i];
  __hip_bfloat16* o = out + (size_t)i * 4;
  o[0] = __float2bfloat16(v.x);
  o[1] = __float2bfloat16(v.y);
  o[2] = __float2bfloat16(v.z);
  o[3] = __float2bfloat16(v.w);
}

// ---------------- RMSNorm: fp32 row -> bf16 row ----------------
__global__ __launch_bounds__(256)
void rmsnorm_kernel(const float* __restrict__ x, const float* __restrict__ w,
                    __hip_bfloat16* __restrict__ out)
{
  int row = blockIdx.x;
  int tid = threadIdx.x;
  const float4 v = ((const float4*)(x + (size_t)row * DIMSZ))[tid];
  float ss = v.x*v.x + v.y*v.y + v.z*v.z + v.w*v.w;
  #pragma unroll
  for (int m = 32; m >= 1; m >>= 1) ss += __shfl_xor(ss, m);
  __shared__ float red[4];
  int wave = tid >> 6, lane = tid & 63;
  if (lane == 0) red[wave] = ss;
  __syncthreads();
  float tot = red[0] + red[1] + red[2] + red[3];
  float sc = rsqrtf(tot * (1.0f / DIMSZ) + 1e-6f);
  const float4 wv = ((const float4*)w)[tid];
  __hip_bfloat16* o = out + (size_t)row * DIMSZ + tid * 4;
  o[0] = __float2bfloat16(v.x * sc * wv.x);
  o[1] = __float2bfloat16(v.y * sc * wv.y);
  o[2] = __float2bfloat16(v.z * sc * wv.z);
  o[3] = __float2bfloat16(v.w * sc * wv.w);
}

// ---------------- GEMM: C[M,N] = A[M,K] * B[N,K]^T, bf16 in, fp32 acc ----------------
template<int EPI>
__global__ __launch_bounds__(256)
void gemm_bt(const __hip_bfloat16* __restrict__ A,
             const __hip_bfloat16* __restrict__ Bw,
             float* __restrict__ Cf,
             __hip_bfloat16* __restrict__ Cb,
             const float* __restrict__ resid,
             int N, int K)
{
  __shared__ __align__(16) __hip_bfloat16 sA[128 * 32];
  __shared__ __align__(16) __hip_bfloat16 sB[128 * 32];
  const int tid = threadIdx.x;
  const int wave = tid >> 6, lane = tid & 63;
  const int lg = lane >> 4, lr15 = lane & 15;
  const int row0 = blockIdx.y * 128, col0 = blockIdx.x * 128;
  const int wr = wave >> 1, wc = wave & 1;
  f32x4 acc[4][4] = {};

  const int ld_r = tid >> 2;          // 0..63
  const int ld_c = (tid & 3) * 8;
  const __hip_bfloat16* gA = A + (size_t)(row0 + ld_r) * K + ld_c;
  const __hip_bfloat16* gB = Bw + (size_t)(col0 + ld_r) * K + ld_c;

  for (int k0 = 0; k0 < K; k0 += 32) {
    gload_lds16(gA + k0,          &sA[(wave * 64) * 8]);
    gload_lds16(gA + 64 * K + k0, &sA[(256 + wave * 64) * 8]);
    gload_lds16(gB + k0,          &sB[(wave * 64) * 8]);
    gload_lds16(gB + 64 * K + k0, &sB[(256 + wave * 64) * 8]);
    __syncthreads();
    bf16x8 af[4], bfr[4];
    #pragma unroll
    for (int m = 0; m < 4; ++m)
      af[m] = *(const bf16x8*)&sA[(wr * 64 + m * 16 + lr15) * 32 + lg * 8];
    #pragma unroll
    for (int n = 0; n < 4; ++n)
      bfr[n] = *(const bf16x8*)&sB[(wc * 64 + n * 16 + lr15) * 32 + lg * 8];
    #pragma unroll
    for (int m = 0; m < 4; ++m)
      #pragma unroll
      for (int n = 0; n < 4; ++n)
        acc[m][n] = MFMA_BF16(af[m], bfr[n], acc[m][n]);
    __syncthreads();
  }

  #pragma unroll
  for (int m = 0; m < 4; ++m) {
    #pragma unroll
    for (int n = 0; n < 4; ++n) {
      #pragma unroll
      for (int r = 0; r < 4; ++r) {
        const int grow = row0 + wr * 64 + m * 16 + lg * 4 + r;
        const int gcol = col0 + wc * 64 + n * 16 + lr15;
        const size_t idx = (size_t)grow * N + gcol;
        const float v = acc[m][n][r];
        if (EPI == 0) {
          Cb[idx] = __float2bfloat16(v);
        } else if (EPI == 1) {
          Cf[idx] = resid[idx] + v;
        } else {
          Cb[idx] = __float2bfloat16(v / (1.0f + __expf(-v)));
        }
      }
    }
  }
}

// ---------------- RoPE on q,k ----------------
__global__ __launch_bounds__(256)
void rope_qk(const __hip_bfloat16* __restrict__ qkv,
             __hip_bfloat16* __restrict__ Q, __hip_bfloat16* __restrict__ Kx)
{
  int idx = blockIdx.x * 256 + threadIdx.x;   // bits: i:5, h:4, s:11, b:1
  int i = idx & 31;
  int h = (idx >> 5) & 15;
  int s = (idx >> 9) & (S_LEN - 1);
  int b = idx >> 20;
  const size_t base = ((size_t)b * S_LEN + s) * 3072 + h * 64 + 2 * i;
  float qe = __bfloat162float(qkv[base]);
  float qo = __bfloat162float(qkv[base + 1]);
  float ke = __bfloat162float(qkv[base + 1024]);
  float ko = __bfloat162float(qkv[base + 1025]);
  float inv = __expf(-(2.0f * i) * (9.210340371976184f / 64.0f));
  float ang = (float)s * inv;
  float sn, cs;
  __sincosf(ang, &sn, &cs);
  const float sc = 0.125f;   // 1/sqrt(HD) folded into Q
  size_t qb = (((size_t)b * NH + h) * S_LEN + s) * HD + 2 * i;
  Q[qb]     = __float2bfloat16((qe * cs - qo * sn) * sc);
  Q[qb + 1] = __float2bfloat16((qo * cs + qe * sn) * sc);
  Kx[qb]     = __float2bfloat16(ke * cs - ko * sn);
  Kx[qb + 1] = __float2bfloat16(ko * cs + ke * sn);
}

// ---------------- V transpose ----------------
__global__ __launch_bounds__(256)
void v_transpose(const __hip_bfloat16* __restrict__ qkv, __hip_bfloat16* __restrict__ Vt)
{
  __shared__ __hip_bfloat16 t[64][72];
  const int s0 = blockIdx.x * 64;
  const int bh = blockIdx.y;
  const int b = bh >> 4, h = bh & 15;
  const int tid = threadIdx.x;
  const int c = tid & 63;
  #pragma unroll
  for (int r = 0; r < 16; ++r) {
    int srow = r * 4 + (tid >> 6);
    t[srow][c] = qkv[((size_t)b * S_LEN + s0 + srow) * 3072 + 2048 + h * 64 + c];
  }
  __syncthreads();
  #pragma unroll
  for (int r = 0; r < 16; ++r) {
    int drow = r * 4 + (tid >> 6);
    Vt[(((size_t)b * NH + h) * HD + drow) * S_LEN + s0 + c] = t[c][drow];
  }
}

__device__ __forceinline__ unsigned bf16pack2(float a, float b) {
  __hip_bfloat16 ha = __float2bfloat16(a), hb = __float2bfloat16(b);
  unsigned ua = *reinterpret_cast<unsigned short*>(&ha);
  unsigned ub = *reinterpret_cast<unsigned short*>(&hb);
  return ua | (ub << 16);
}

// ---------------- flash attention v3: 4 waves/block, LDS-staged K/V, dbuf prefetch ----
// Block: 256 threads, 64 q-rows (wave w owns q0+16w .. +16). KVBLK=64.
// K tile [64 k][64 d] and Vt tile [64 d][64 k] staged via global_load_lds with
// inverse-XOR-swizzled SOURCE addresses (linear LDS dest); ds_read_b128 at
// XOR-swizzled col -> conflict-free. Double-buffered: stage(st+1) issued before
// compute(st); __syncthreads (vmcnt0+barrier) at step end hides L2 latency.
// Softmax: swapped QK^T (S^T in regs), unnormalized exp, in-lane denominator,
// one shuffle-reduce at the end. P -> A-frag via per-wave 2KB swizzled LDS.
__global__ __launch_bounds__(256, 4)
void flash_attn3(const __hip_bfloat16* __restrict__ Q,
                 const __hip_bfloat16* __restrict__ Kx,
                 const __hip_bfloat16* __restrict__ Vt,
                 __hip_bfloat16* __restrict__ attn)
{
  __shared__ __align__(16) char sK[2][8192];
  __shared__ __align__(16) char sV[2][8192];
  __shared__ __align__(16) char sP[4][2048];

  const int tid = threadIdx.x;
  const int w = tid >> 6;           // wave 0..3
  const int lane = tid & 63;
  const int lg = lane >> 4, lr = lane & 15;
  const int bid = blockIdx.x;
  const int bh = bid & 31;          // b*16+h
  const int b = bh >> 4, h = bh & 15;
  const int j = bid >> 5;           // 0..31
  const int m = j >> 3, a = j & 7;
  const int xm = (0x6170 >> (m << 2)) & 7;   // {0,7,1,6}: per-CU causal-load balance
  const int qb = m * 8 + (a ^ xm);
  const int q0 = qb * 64;
  const int nsteps = qb + 1;

  const char* Kb = (const char*)(Kx + (size_t)bh * S_LEN * HD);   // [S][64] bf16
  const char* Vb = (const char*)(Vt + (size_t)bh * HD * S_LEN);   // [64][S] bf16
  const __hip_bfloat16* Qp = Q + (size_t)bh * S_LEN * HD;

  const int q0w = q0 + w * 16;
  const bf16x8 qf0 = *(const bf16x8*)&Qp[(q0w + lr) * HD + lg * 8];
  const bf16x8 qf1 = *(const bf16x8*)&Qp[(q0w + lr) * HD + 32 + lg * 8];
  char* sPw = sP[w];
  const int swzr = (lr & 7) << 4;
  const int wbase = (tid & 192) << 4;     // wave*64 chunks *16 B

  f32x4 acc[4] = {};
  float lsum = 0.f;
  int cur = 0;

  // stage step 0
  #pragma unroll
  for (int i = 0; i < 2; ++i) {
    const int c = i * 256 + tid;
    const int row = c >> 3;
    const int scol = ((c & 7) << 4) ^ ((row & 7) << 4);
    gload_lds16(Kb + (size_t)row * 128 + scol, sK[0] + i * 4096 + wbase);
    gload_lds16(Vb + (size_t)row * (S_LEN * 2) + scol, sV[0] + i * 4096 + wbase);
  }
  __syncthreads();

  for (int st = 0; st < nsteps; ++st) {
    if (st + 1 < nsteps) {
      const int kn = (st + 1) * 64;
      #pragma unroll
      for (int i = 0; i < 2; ++i) {
        const int c = i * 256 + tid;
        const int row = c >> 3;
        const int scol = ((c & 7) << 4) ^ ((row & 7) << 4);
        gload_lds16(Kb + (size_t)(kn + row) * 128 + scol, sK[cur ^ 1] + i * 4096 + wbase);
        gload_lds16(Vb + (size_t)row * (S_LEN * 2) + (size_t)kn * 2 + scol, sV[cur ^ 1] + i * 4096 + wbase);
      }
    }
    const int k0 = st * 64;
    const char* pK = sK[cur];
    const char* pV = sV[cur];
    // --- QK^T (swapped): S^T[k][q] frags ---
    f32x4 sv[4];
    #pragma unroll
    for (int t = 0; t < 4; ++t) {
      const int rb = (t * 16 + lr) * 128;
      const bf16x8 kf0 = *(const bf16x8*)(pK + rb + ((lg * 16) ^ swzr));
      const bf16x8 kf1 = *(const bf16x8*)(pK + rb + ((64 + lg * 16) ^ swzr));
      f32x4 z = {};
      z = MFMA_BF16(kf0, qf0, z);
      z = MFMA_BF16(kf1, qf1, z);
      sv[t] = z;
    }
    // --- P = exp(S); in-lane denominator; write P to per-wave LDS ---
    const bool maskstep = (st == nsteps - 1);
    #pragma unroll
    for (int t = 0; t < 4; ++t) {
      float p[4];
      #pragma unroll
      for (int r = 0; r < 4; ++r) {
        float e = __expf(fminf(sv[t][r], 30.f));
        if (maskstep) {
          const int kg = k0 + t * 16 + lg * 4 + r;
          e = (kg <= q0w + lr) ? e : 0.f;
        }
        lsum += e;
        p[r] = e;
      }
      uint2 wv2;
      wv2.x = bf16pack2(p[0], p[1]);
      wv2.y = bf16pack2(p[2], p[3]);
      *(uint2*)(sPw + lr * 128 + ((t * 32 + lg * 8) ^ swzr)) = wv2;
    }
    asm volatile("s_waitcnt lgkmcnt(0)" ::: "memory");
    __builtin_amdgcn_sched_barrier(0);
    // --- PV ---
    const bf16x8 pa0 = *(const bf16x8*)(sPw + lr * 128 + ((lg * 16) ^ swzr));
    const bf16x8 pa1 = *(const bf16x8*)(sPw + lr * 128 + ((64 + lg * 16) ^ swzr));
    #pragma unroll
    for (int dt = 0; dt < 4; ++dt) {
      const int rb = (dt * 16 + lr) * 128;
      const bf16x8 vf0 = *(const bf16x8*)(pV + rb + ((lg * 16) ^ swzr));
      const bf16x8 vf1 = *(const bf16x8*)(pV + rb + ((64 + lg * 16) ^ swzr));
      acc[dt] = MFMA_BF16(pa0, vf0, acc[dt]);
      acc[dt] = MFMA_BF16(pa1, vf1, acc[dt]);
    }
    __syncthreads();     // drains vmcnt(0): next-step staging complete; dbuf safe
    cur ^= 1;
  }

  // reduce denominator across the 4 lane-groups (q = lr)
  lsum += __shfl_xor(lsum, 16);
  lsum += __shfl_xor(lsum, 32);
  #pragma unroll
  for (int r = 0; r < 4; ++r) {
    const float li = __shfl(lsum, lg * 4 + r);   // denominator for q = q0w + lg*4+r
    const float rli = 1.0f / li;
    const size_t rowb = ((size_t)b * S_LEN + q0w + lg * 4 + r) * DIMSZ + h * HD;
    #pragma unroll
    for (int dt = 0; dt < 4; ++dt)
      attn[rowb + dt * 16 + lr] = __float2bfloat16(acc[dt][r] * rli);
  }
}

extern "C" void kernel_launch(void* const* d_in, const int* in_sizes, int n_in,
                              void* d_out, int out_size, void* d_ws, size_t ws_size,
                              hipStream_t stream)
{
  const float* x      = (const float*)d_in[0];
  const float* w_in   = (const float*)d_in[1];
  const float* w_ff   = (const float*)d_in[2];
  const float* w_qkv  = (const float*)d_in[3];
  const float* w_out  = (const float*)d_in[4];
  const float* w_fc   = (const float*)d_in[5];
  const float* w_proj = (const float*)d_in[6];
  float* out = (float*)d_out;
  char* ws = (char*)d_ws;

  __hip_bfloat16* wq_b   = (__hip_bfloat16*)(ws);               // 6,291,456
  __hip_bfloat16* wo_b   = (__hip_bfloat16*)(ws + 6291456);     // 2,097,152
  __hip_bfloat16* wfc_b  = (__hip_bfloat16*)(ws + 8388608);     // 4,194,304
  __hip_bfloat16* wpr_b  = (__hip_bfloat16*)(ws + 12582912);    // 4,194,304
  __hip_bfloat16* h_b    = (__hip_bfloat16*)(ws + 16777216);    // 8,388,608
  __hip_bfloat16* qkv_b  = (__hip_bfloat16*)(ws + 25165824);    // 25,165,824
  __hip_bfloat16* attn_b = (__hip_bfloat16*)(ws + 25165824);    // reuse qkv[0:8M]
  __hip_bfloat16* hid_b  = (__hip_bfloat16*)(ws + 33554432);    // reuse qkv[8M:24M]
  __hip_bfloat16* Q_b    = (__hip_bfloat16*)(ws + 50331648);    // 8,388,608
  __hip_bfloat16* K_b    = (__hip_bfloat16*)(ws + 58720256);    // 8,388,608
  __hip_bfloat16* Vt_b   = (__hip_bfloat16*)(ws + 67108864);    // 8,388,608
  float*          x1     = (float*)(ws + 50331648);             // reuse Q+K after flash

  cast_bf16_kernel<<<(3072 * 1024 / 4 + 255) / 256, 256, 0, stream>>>(w_qkv, wq_b, 3072 * 1024 / 4);
  cast_bf16_kernel<<<(1024 * 1024 / 4 + 255) / 256, 256, 0, stream>>>(w_out, wo_b, 1024 * 1024 / 4);
  cast_bf16_kernel<<<(2048 * 1024 / 4 + 255) / 256, 256, 0, stream>>>(w_fc, wfc_b, 2048 * 1024 / 4);
  cast_bf16_kernel<<<(1024 * 2048 / 4 + 255) / 256, 256, 0, stream>>>(w_proj, wpr_b, 1024 * 2048 / 4);
  rmsnorm_kernel<<<4096, 256, 0, stream>>>(x, w_in, h_b);
  gemm_bt<0><<<dim3(3072 / 128, 4096 / 128), 256, 0, stream>>>(h_b, wq_b, nullptr, qkv_b, nullptr, 3072, 1024);
  rope_qk<<<2097152 / 256, 256, 0, stream>>>(qkv_b, Q_b, K_b);
  v_transpose<<<dim3(32, 32), 256, 0, stream>>>(qkv_b, Vt_b);
  flash_attn3<<<1024, 256, 0, stream>>>(Q_b, K_b, Vt_b, attn_b);
  gemm_bt<1><<<dim3(1024 / 128, 4096 / 128), 256, 0, stream>>>(attn_b, wo_b, x1, nullptr, x, 1024, 1024);
  rmsnorm_kernel<<<4096, 256, 0, stream>>>(x1, w_ff, h_b);
  gemm_bt<2><<<dim3(2048 / 128, 4096 / 128), 256, 0, stream>>>(h_b, wfc_b, nullptr, hid_b, nullptr, 2048, 1024);
  gemm_bt<1><<<dim3(1024 / 128, 4096 / 128), 256, 0, stream>>>(hid_b, wpr_b, out, nullptr, x1, 1024, 2048);
}

// Round 4
// 174.802 us; speedup vs baseline: 2.3302x; 1.2504x over previous
//
#include <hip/hip_runtime.h>
#include <hip/hip_bf16.h>
#include <cstdint>

#define DIMSZ 1024
#define S_LEN 2048
#define NH 16
#define HD 64

typedef __attribute__((ext_vector_type(4))) float f32x4;
typedef __attribute__((ext_vector_type(8))) __bf16 bf16x8;

#define MFMA_BF16(a,b,c) __builtin_amdgcn_mfma_f32_16x16x32_bf16((a),(b),(c),0,0,0)

__device__ __forceinline__ void gload_lds16(const void* g, void* l) {
  __builtin_amdgcn_global_load_lds(
      (const __attribute__((address_space(1))) unsigned int*)(uintptr_t)g,
      (__attribute__((address_space(3))) unsigned int*)(uintptr_t)l,
      16, 0, 0);
}

// ---------------- fused cast fp32 -> bf16 for all 4 weights ----------------
__global__ __launch_bounds__(256)
void cast_all_kernel(const float* __restrict__ s0, const float* __restrict__ s1,
                     const float* __restrict__ s2, const float* __restrict__ s3,
                     __hip_bfloat16* __restrict__ d0, __hip_bfloat16* __restrict__ d1,
                     __hip_bfloat16* __restrict__ d2, __hip_bfloat16* __restrict__ d3)
{
  int i = blockIdx.x * 256 + threadIdx.x;   // float4 index, total 2097152
  const float* s; __hip_bfloat16* d; int off;
  if (i < 786432)       { s = s0; d = d0; off = i; }
  else if (i < 1048576) { s = s1; d = d1; off = i - 786432; }
  else if (i < 1572864) { s = s2; d = d2; off = i - 1048576; }
  else                  { s = s3; d = d3; off = i - 1572864; }
  float4 v = ((const float4*)s)[off];
  __hip_bfloat16* o = d + (size_t)off * 4;
  o[0] = __float2bfloat16(v.x);
  o[1] = __float2bfloat16(v.y);
  o[2] = __float2bfloat16(v.z);
  o[3] = __float2bfloat16(v.w);
}

// ---------------- RMSNorm: fp32 row -> bf16 row ----------------
__global__ __launch_bounds__(256)
void rmsnorm_kernel(const float* __restrict__ x, const float* __restrict__ w,
                    __hip_bfloat16* __restrict__ out)
{
  int row = blockIdx.x;
  int tid = threadIdx.x;
  const float4 v = ((const float4*)(x + (size_t)row * DIMSZ))[tid];
  float ss = v.x*v.x + v.y*v.y + v.z*v.z + v.w*v.w;
  #pragma unroll
  for (int m = 32; m >= 1; m >>= 1) ss += __shfl_xor(ss, m);
  __shared__ float red[4];
  int wave = tid >> 6, lane = tid & 63;
  if (lane == 0) red[wave] = ss;
  __syncthreads();
  float tot = red[0] + red[1] + red[2] + red[3];
  float sc = rsqrtf(tot * (1.0f / DIMSZ) + 1e-6f);
  const float4 wv = ((const float4*)w)[tid];
  __hip_bfloat16* o = out + (size_t)row * DIMSZ + tid * 4;
  o[0] = __float2bfloat16(v.x * sc * wv.x);
  o[1] = __float2bfloat16(v.y * sc * wv.y);
  o[2] = __float2bfloat16(v.z * sc * wv.z);
  o[3] = __float2bfloat16(v.w * sc * wv.w);
}

// ---------------- GEMM v2: C[M,N] = A[M,K] * B[N,K]^T, bf16 in, fp32 acc ----------
// 128x128 tile, BK=64, double-buffered LDS staged via global_load_lds (width 16)
// with inverse-XOR-swizzled SOURCE addresses (linear LDS dest); reads use the
// same XOR -> conflict-free ds_read_b128. 2-phase pipeline: STAGE(st+1) issued
// before compute(st); ONE __syncthreads per K-step (vmcnt drain doubles as the
// dbuf handoff). 32 MFMA per barrier.
template<int EPI>
__global__ __launch_bounds__(256, 2)
void gemm_bt2(const __hip_bfloat16* __restrict__ A,
              const __hip_bfloat16* __restrict__ Bw,
              float* __restrict__ Cf,
              __hip_bfloat16* __restrict__ Cb,
              const float* __restrict__ resid,
              int N, int K)
{
  __shared__ __align__(16) char sA[2][16384];   // [128 rows][128 B]
  __shared__ __align__(16) char sB[2][16384];
  const int tid = threadIdx.x;
  const int wave = tid >> 6, lane = tid & 63;
  const int lg = lane >> 4, lr15 = lane & 15;
  const int row0 = blockIdx.y * 128, col0 = blockIdx.x * 128;
  const int wr = wave >> 1, wc = wave & 1;
  f32x4 acc[4][4] = {};

  const size_t Kb = (size_t)K * 2;         // global row stride (bytes)
  const int rown = tid >> 3;               // 0..31 (row within 32-row chunk)
  const int scol = ((tid & 7) << 4) ^ ((rown & 7) << 4);   // pre-swizzled source col
  const char* gA = (const char*)A + (size_t)(row0 + rown) * Kb + scol;
  const char* gB = (const char*)Bw + (size_t)(col0 + rown) * Kb + scol;
  const int dbase = wave * 1024;           // wave-uniform LDS chunk base (per it: +4096)

  const int nsteps = K >> 6;
  int cur = 0;

#define STAGE_G(buf, st) do {                                              \
    const size_t kb_ = (size_t)(st) * 128;                                 \
    _Pragma("unroll")                                                      \
    for (int it = 0; it < 4; ++it) {                                       \
      gload_lds16(gA + (size_t)(it * 32) * Kb + kb_, &sA[buf][it * 4096 + dbase]); \
      gload_lds16(gB + (size_t)(it * 32) * Kb + kb_, &sB[buf][it * 4096 + dbase]); \
    }                                                                      \
  } while (0)

  STAGE_G(0, 0);
  __syncthreads();

  const int swz = (lr15 & 7) << 4;
  for (int st = 0; st < nsteps; ++st) {
    if (st + 1 < nsteps) STAGE_G(cur ^ 1, st + 1);
    const char* pA = sA[cur];
    const char* pB = sB[cur];
    bf16x8 af[2][4], bfr[2][4];
    #pragma unroll
    for (int m = 0; m < 4; ++m) {
      const int ra = (wr * 64 + m * 16 + lr15) * 128;
      af[0][m] = *(const bf16x8*)(pA + ra + ((lg * 16) ^ swz));
      af[1][m] = *(const bf16x8*)(pA + ra + ((64 + lg * 16) ^ swz));
      const int rb = (wc * 64 + m * 16 + lr15) * 128;
      bfr[0][m] = *(const bf16x8*)(pB + rb + ((lg * 16) ^ swz));
      bfr[1][m] = *(const bf16x8*)(pB + rb + ((64 + lg * 16) ^ swz));
    }
    #pragma unroll
    for (int kh = 0; kh < 2; ++kh)
      #pragma unroll
      for (int m = 0; m < 4; ++m)
        #pragma unroll
        for (int n = 0; n < 4; ++n)
          acc[m][n] = MFMA_BF16(af[kh][m], bfr[kh][n], acc[m][n]);
    __syncthreads();     // drains vmcnt(0): stage(st+1) landed; dbuf safe
    cur ^= 1;
  }
#undef STAGE_G

  #pragma unroll
  for (int m = 0; m < 4; ++m) {
    #pragma unroll
    for (int n = 0; n < 4; ++n) {
      #pragma unroll
      for (int r = 0; r < 4; ++r) {
        const int grow = row0 + wr * 64 + m * 16 + lg * 4 + r;
        const int gcol = col0 + wc * 64 + n * 16 + lr15;
        const size_t idx = (size_t)grow * N + gcol;
        const float v = acc[m][n][r];
        if (EPI == 0) {
          Cb[idx] = __float2bfloat16(v);
        } else if (EPI == 1) {
          Cf[idx] = resid[idx] + v;
        } else {
          Cb[idx] = __float2bfloat16(v / (1.0f + __expf(-v)));
        }
      }
    }
  }
}

// ---------------- RoPE on q,k ----------------
__global__ __launch_bounds__(256)
void rope_qk(const __hip_bfloat16* __restrict__ qkv,
             __hip_bfloat16* __restrict__ Q, __hip_bfloat16* __restrict__ Kx)
{
  int idx = blockIdx.x * 256 + threadIdx.x;   // bits: i:5, h:4, s:11, b:1
  int i = idx & 31;
  int h = (idx >> 5) & 15;
  int s = (idx >> 9) & (S_LEN - 1);
  int b = idx >> 20;
  const size_t base = ((size_t)b * S_LEN + s) * 3072 + h * 64 + 2 * i;
  float qe = __bfloat162float(qkv[base]);
  float qo = __bfloat162float(qkv[base + 1]);
  float ke = __bfloat162float(qkv[base + 1024]);
  float ko = __bfloat162float(qkv[base + 1025]);
  float inv = __expf(-(2.0f * i) * (9.210340371976184f / 64.0f));
  float ang = (float)s * inv;
  float sn, cs;
  __sincosf(ang, &sn, &cs);
  const float sc = 0.125f;   // 1/sqrt(HD) folded into Q
  size_t qb = (((size_t)b * NH + h) * S_LEN + s) * HD + 2 * i;
  Q[qb]     = __float2bfloat16((qe * cs - qo * sn) * sc);
  Q[qb + 1] = __float2bfloat16((qo * cs + qe * sn) * sc);
  Kx[qb]     = __float2bfloat16(ke * cs - ko * sn);
  Kx[qb + 1] = __float2bfloat16(ko * cs + ke * sn);
}

// ---------------- V transpose ----------------
__global__ __launch_bounds__(256)
void v_transpose(const __hip_bfloat16* __restrict__ qkv, __hip_bfloat16* __restrict__ Vt)
{
  __shared__ __hip_bfloat16 t[64][72];
  const int s0 = blockIdx.x * 64;
  const int bh = blockIdx.y;
  const int b = bh >> 4, h = bh & 15;
  const int tid = threadIdx.x;
  const int c = tid & 63;
  #pragma unroll
  for (int r = 0; r < 16; ++r) {
    int srow = r * 4 + (tid >> 6);
    t[srow][c] = qkv[((size_t)b * S_LEN + s0 + srow) * 3072 + 2048 + h * 64 + c];
  }
  __syncthreads();
  #pragma unroll
  for (int r = 0; r < 16; ++r) {
    int drow = r * 4 + (tid >> 6);
    Vt[(((size_t)b * NH + h) * HD + drow) * S_LEN + s0 + c] = t[c][drow];
  }
}

__device__ __forceinline__ unsigned bf16pack2(float a, float b) {
  __hip_bfloat16 ha = __float2bfloat16(a), hb = __float2bfloat16(b);
  unsigned ua = *reinterpret_cast<unsigned short*>(&ha);
  unsigned ub = *reinterpret_cast<unsigned short*>(&hb);
  return ua | (ub << 16);
}

// ---------------- flash attention v3 (unchanged, verified) ----------------
__global__ __launch_bounds__(256, 4)
void flash_attn3(const __hip_bfloat16* __restrict__ Q,
                 const __hip_bfloat16* __restrict__ Kx,
                 const __hip_bfloat16* __restrict__ Vt,
                 __hip_bfloat16* __restrict__ attn)
{
  __shared__ __align__(16) char sK[2][8192];
  __shared__ __align__(16) char sV[2][8192];
  __shared__ __align__(16) char sP[4][2048];

  const int tid = threadIdx.x;
  const int w = tid >> 6;           // wave 0..3
  const int lane = tid & 63;
  const int lg = lane >> 4, lr = lane & 15;
  const int bid = blockIdx.x;
  const int bh = bid & 31;          // b*16+h
  const int b = bh >> 4, h = bh & 15;
  const int j = bid >> 5;           // 0..31
  const int m = j >> 3, a = j & 7;
  const int xm = (0x6170 >> (m << 2)) & 7;   // {0,7,1,6}: per-CU causal-load balance
  const int qb = m * 8 + (a ^ xm);
  const int q0 = qb * 64;
  const int nsteps = qb + 1;

  const char* Kb = (const char*)(Kx + (size_t)bh * S_LEN * HD);   // [S][64] bf16
  const char* Vb = (const char*)(Vt + (size_t)bh * HD * S_LEN);   // [64][S] bf16
  const __hip_bfloat16* Qp = Q + (size_t)bh * S_LEN * HD;

  const int q0w = q0 + w * 16;
  const bf16x8 qf0 = *(const bf16x8*)&Qp[(q0w + lr) * HD + lg * 8];
  const bf16x8 qf1 = *(const bf16x8*)&Qp[(q0w + lr) * HD + 32 + lg * 8];
  char* sPw = sP[w];
  const int swzr = (lr & 7) << 4;
  const int wbase = (tid & 192) << 4;     // wave*64 chunks *16 B

  f32x4 acc[4] = {};
  float lsum = 0.f;
  int cur = 0;

  #pragma unroll
  for (int i = 0; i < 2; ++i) {
    const int c = i * 256 + tid;
    const int row = c >> 3;
    const int scol = ((c & 7) << 4) ^ ((row & 7) << 4);
    gload_lds16(Kb + (size_t)row * 128 + scol, sK[0] + i * 4096 + wbase);
    gload_lds16(Vb + (size_t)row * (S_LEN * 2) + scol, sV[0] + i * 4096 + wbase);
  }
  __syncthreads();

  for (int st = 0; st < nsteps; ++st) {
    if (st + 1 < nsteps) {
      const int kn = (st + 1) * 64;
      #pragma unroll
      for (int i = 0; i < 2; ++i) {
        const int c = i * 256 + tid;
        const int row = c >> 3;
        const int scol = ((c & 7) << 4) ^ ((row & 7) << 4);
        gload_lds16(Kb + (size_t)(kn + row) * 128 + scol, sK[cur ^ 1] + i * 4096 + wbase);
        gload_lds16(Vb + (size_t)row * (S_LEN * 2) + (size_t)kn * 2 + scol, sV[cur ^ 1] + i * 4096 + wbase);
      }
    }
    const int k0 = st * 64;
    const char* pK = sK[cur];
    const char* pV = sV[cur];
    f32x4 sv[4];
    #pragma unroll
    for (int t = 0; t < 4; ++t) {
      const int rb = (t * 16 + lr) * 128;
      const bf16x8 kf0 = *(const bf16x8*)(pK + rb + ((lg * 16) ^ swzr));
      const bf16x8 kf1 = *(const bf16x8*)(pK + rb + ((64 + lg * 16) ^ swzr));
      f32x4 z = {};
      z = MFMA_BF16(kf0, qf0, z);
      z = MFMA_BF16(kf1, qf1, z);
      sv[t] = z;
    }
    const bool maskstep = (st == nsteps - 1);
    #pragma unroll
    for (int t = 0; t < 4; ++t) {
      float p[4];
      #pragma unroll
      for (int r = 0; r < 4; ++r) {
        float e = __expf(fminf(sv[t][r], 30.f));
        if (maskstep) {
          const int kg = k0 + t * 16 + lg * 4 + r;
          e = (kg <= q0w + lr) ? e : 0.f;
        }
        lsum += e;
        p[r] = e;
      }
      uint2 wv2;
      wv2.x = bf16pack2(p[0], p[1]);
      wv2.y = bf16pack2(p[2], p[3]);
      *(uint2*)(sPw + lr * 128 + ((t * 32 + lg * 8) ^ swzr)) = wv2;
    }
    asm volatile("s_waitcnt lgkmcnt(0)" ::: "memory");
    __builtin_amdgcn_sched_barrier(0);
    const bf16x8 pa0 = *(const bf16x8*)(sPw + lr * 128 + ((lg * 16) ^ swzr));
    const bf16x8 pa1 = *(const bf16x8*)(sPw + lr * 128 + ((64 + lg * 16) ^ swzr));
    #pragma unroll
    for (int dt = 0; dt < 4; ++dt) {
      const int rb = (dt * 16 + lr) * 128;
      const bf16x8 vf0 = *(const bf16x8*)(pV + rb + ((lg * 16) ^ swzr));
      const bf16x8 vf1 = *(const bf16x8*)(pV + rb + ((64 + lg * 16) ^ swzr));
      acc[dt] = MFMA_BF16(pa0, vf0, acc[dt]);
      acc[dt] = MFMA_BF16(pa1, vf1, acc[dt]);
    }
    __syncthreads();
    cur ^= 1;
  }

  lsum += __shfl_xor(lsum, 16);
  lsum += __shfl_xor(lsum, 32);
  #pragma unroll
  for (int r = 0; r < 4; ++r) {
    const float li = __shfl(lsum, lg * 4 + r);
    const float rli = 1.0f / li;
    const size_t rowb = ((size_t)b * S_LEN + q0w + lg * 4 + r) * DIMSZ + h * HD;
    #pragma unroll
    for (int dt = 0; dt < 4; ++dt)
      attn[rowb + dt * 16 + lr] = __float2bfloat16(acc[dt][r] * rli);
  }
}

extern "C" void kernel_launch(void* const* d_in, const int* in_sizes, int n_in,
                              void* d_out, int out_size, void* d_ws, size_t ws_size,
                              hipStream_t stream)
{
  const float* x      = (const float*)d_in[0];
  const float* w_in   = (const float*)d_in[1];
  const float* w_ff   = (const float*)d_in[2];
  const float* w_qkv  = (const float*)d_in[3];
  const float* w_out  = (const float*)d_in[4];
  const float* w_fc   = (const float*)d_in[5];
  const float* w_proj = (const float*)d_in[6];
  float* out = (float*)d_out;
  char* ws = (char*)d_ws;

  __hip_bfloat16* wq_b   = (__hip_bfloat16*)(ws);               // 6,291,456
  __hip_bfloat16* wo_b   = (__hip_bfloat16*)(ws + 6291456);     // 2,097,152
  __hip_bfloat16* wfc_b  = (__hip_bfloat16*)(ws + 8388608);     // 4,194,304
  __hip_bfloat16* wpr_b  = (__hip_bfloat16*)(ws + 12582912);    // 4,194,304
  __hip_bfloat16* h_b    = (__hip_bfloat16*)(ws + 16777216);    // 8,388,608
  __hip_bfloat16* qkv_b  = (__hip_bfloat16*)(ws + 25165824);    // 25,165,824
  __hip_bfloat16* attn_b = (__hip_bfloat16*)(ws + 25165824);    // reuse qkv[0:8M]
  __hip_bfloat16* hid_b  = (__hip_bfloat16*)(ws + 33554432);    // reuse qkv[8M:24M]
  __hip_bfloat16* Q_b    = (__hip_bfloat16*)(ws + 50331648);    // 8,388,608
  __hip_bfloat16* K_b    = (__hip_bfloat16*)(ws + 58720256);    // 8,388,608
  __hip_bfloat16* Vt_b   = (__hip_bfloat16*)(ws + 67108864);    // 8,388,608
  float*          x1     = (float*)(ws + 50331648);             // reuse Q+K after flash

  cast_all_kernel<<<8192, 256, 0, stream>>>(w_qkv, w_out, w_fc, w_proj, wq_b, wo_b, wfc_b, wpr_b);
  rmsnorm_kernel<<<4096, 256, 0, stream>>>(x, w_in, h_b);
  gemm_bt2<0><<<dim3(3072 / 128, 4096 / 128), 256, 0, stream>>>(h_b, wq_b, nullptr, qkv_b, nullptr, 3072, 1024);
  rope_qk<<<2097152 / 256, 256, 0, stream>>>(qkv_b, Q_b, K_b);
  v_transpose<<<dim3(32, 32), 256, 0, stream>>>(qkv_b, Vt_b);
  flash_attn3<<<1024, 256, 0, stream>>>(Q_b, K_b, Vt_b, attn_b);
  gemm_bt2<1><<<dim3(1024 / 128, 4096 / 128), 256, 0, stream>>>(attn_b, wo_b, x1, nullptr, x, 1024, 1024);
  rmsnorm_kernel<<<4096, 256, 0, stream>>>(x1, w_ff, h_b);
  gemm_bt2<2><<<dim3(2048 / 128, 4096 / 128), 256, 0, stream>>>(h_b, wfc_b, nullptr, hid_b, nullptr, 2048, 1024);
  gemm_bt2<1><<<dim3(1024 / 128, 4096 / 128), 256, 0, stream>>>(hid_b, wpr_b, out, nullptr, x1, 1024, 2048);
}